// Round 5
// baseline (477.269 us; speedup 1.0000x reference)
//
#include <hip/hip_runtime.h>
#include <stdint.h>

#define HW 16384
#define CCH 256
#define NROWS 131072          // 4 pairs * 16384 px * 2 views (interleaved rows)
#define GROUP_ELEMS 524288    // 32 ch * 16384 px
#define BK 64
#define LDSP 72               // proj staging row stride (bf16): 144 B, 16B aligned

typedef __attribute__((ext_vector_type(8))) short bfrag8;
typedef __attribute__((ext_vector_type(8))) unsigned short us8;
typedef __attribute__((ext_vector_type(4))) float facc4;

static __device__ __forceinline__ unsigned short f2b(float f) {
  union { float f; unsigned int u; } x; x.f = f;
  unsigned int r = x.u + 0x7FFFu + ((x.u >> 16) & 1u);
  return (unsigned short)(r >> 16);
}
static __device__ __forceinline__ float b2f(unsigned short h) {
  union { float f; unsigned int u; } x; x.u = ((unsigned int)h) << 16;
  return x.f;
}

// ---------------- GroupNorm stats ----------------
__global__ void k_red(const float* __restrict__ x, float* __restrict__ red) {
  int gg = blockIdx.x >> 3, sp = blockIdx.x & 7;   // 64 groups x 8 splits
  const float4* p = (const float4*)(x + (size_t)gg * GROUP_ELEMS + (size_t)sp * 65536);
  float s = 0.f, ss = 0.f;
  for (int i = 0; i < 64; ++i) {
    float4 v = p[i * 256 + threadIdx.x];
    s  += v.x + v.y + v.z + v.w;
    ss += v.x*v.x + v.y*v.y + v.z*v.z + v.w*v.w;
  }
  for (int off = 32; off; off >>= 1) { s += __shfl_xor(s, off); ss += __shfl_xor(ss, off); }
  __shared__ float ls[4], lss[4];
  int w = threadIdx.x >> 6;
  if ((threadIdx.x & 63) == 0) { ls[w] = s; lss[w] = ss; }
  __syncthreads();
  if (threadIdx.x == 0) {
    float S = ls[0]+ls[1]+ls[2]+ls[3], SS = lss[0]+lss[1]+lss[2]+lss[3];
    atomicAdd(&red[gg*2], S); atomicAdd(&red[gg*2+1], SS);
  }
}

__global__ void k_fin(const float* __restrict__ red, float* __restrict__ stats) {
  int g = threadIdx.x;
  float s = red[g*2], ss = red[g*2+1];
  float mean = s / (float)GROUP_ELEMS;
  float var = ss / (float)GROUP_ELEMS - mean*mean;
  stats[g*2] = mean;
  stats[g*2+1] = rsqrtf(var + 1e-5f);
}

// ------- weight cast -------
// wqb fragment-major: [h][kk=0..7][j=0..11][lane][8], frag = 512 shorts.
// Fragment lane (lm,q4) holds W-row (j*16+lm), k-elems kk*32 + q4*8 + e.
// wpb: plain [256][256] bf16 (proj unchanged).
__global__ void k_cast(const float* __restrict__ wq, const float* __restrict__ wp,
                       unsigned short* __restrict__ wqb, unsigned short* __restrict__ wpb) {
  int i = blockIdx.x * 256 + threadIdx.x;   // grid 1024 -> 262144 = 196608 + 65536 exactly
  if (i < 768*256) {
    int h = i / 49152;
    int rem = i % 49152;
    int kk = rem / 6144;                // 0..7
    int rem2 = rem % 6144;
    int j = rem2 >> 9;                  // 0..11
    int lane = (rem2 >> 3) & 63;
    int e = rem2 & 7;
    int q4 = lane >> 4, lm = lane & 15;
    int cl = j*16 + lm;                 // head-local output col 0..191
    int part = cl >> 6, d = cl & 63;
    int o = part*256 + h*64 + d;        // original wq row
    int k = kk*32 + q4*8 + e;
    wqb[i] = f2b(wq[o*256 + k]);
  } else {
    int j = i - 768*256;
    wpb[j] = f2b(wp[j]);
  }
}

// ---- norm + transpose: x[bv][c][p] fp32 -> xnt fragment-major bf16 ----
// Logical GEMM row R = pair*32768 + P*2 + v (P = pixel, v = view).
// Panel n = R>>4 (4096 shorts); within panel, kk-block (512 shorts) holds
// 16 slots x 32 channels. Slot s holds logical row 16n + sigma(s),
// sigma(s) = 2*(s&7) + (s>>3)  (view = s>>3 -> cross-view partner = lane^8).
// addr_shorts = n*4096 + kk*512 + q4*128 + s*8 + e, channel c = kk*32+q4*8+e.
__global__ void k_norm_t(const float* __restrict__ x, const float* __restrict__ stats,
                         const float* __restrict__ gamma, const float* __restrict__ beta,
                         unsigned short* __restrict__ xnt) {
  __shared__ float tile[64][65];
  int bx = blockIdx.x;               // 8192 blocks: bv(8) x ptile(256) x ctile(4)
  int bv = bx >> 10;
  int rem = bx & 1023;
  int p0 = (rem >> 2) * 64, c0 = (rem & 3) * 64;
  int pair = bv >> 1, v = bv & 1;
  int t = threadIdx.x;
  int p_off = t & 63, c4 = t >> 6;
  const float* xsrc = x + (size_t)bv * CCH * HW;
  for (int cc = 0; cc < 16; ++cc) {
    int c_loc = c4 * 16 + cc;
    int c = c0 + c_loc;
    float val = xsrc[(size_t)c * HW + p0 + p_off];
    int g = bv * 8 + (c >> 5);
    float xn = (val - stats[g*2]) * stats[g*2+1] * gamma[c] + beta[c];
    tile[p_off][c_loc] = xn;
  }
  __syncthreads();
  for (int it = 0; it < 8; ++it) {
    int u = it * 256 + t;
    int p = u >> 5, c2 = u & 31;
    int c = c0 + c2*2;
    unsigned int pk = (unsigned int)f2b(tile[p][c2*2]) | ((unsigned int)f2b(tile[p][c2*2+1]) << 16);
    int P = p0 + p;                          // pixel within pair
    int n = pair*2048 + (P >> 3);            // panel
    int s = (P & 7) + 8*v;                   // slot within panel
    size_t addr = (size_t)n*4096 + (size_t)(c >> 5)*512 + (size_t)((c & 31) >> 3)*128
                + (size_t)s*8 + (c & 7);
    *(unsigned int*)(xnt + addr) = pk;
  }
}

// ------- fused QKV GEMM + cross-view attention: LDS-free, barrier-free -------
// Wave owns 32 rows (2 panels) x 192 cols (one head); acc[2][12] = 96 VGPR.
// All fragments load directly from global as contiguous 1KB wave loads
// (fragment-major layouts above). B (12KB/step) is L1-resident, shared by all
// waves/blocks of the same head. Swapped-operand MFMA: lane&15 = row slot,
// (lane>>4)*4+reg = col-within-16. Slot order sigma puts the cross-view
// partner at lane^8. Bias folded into acc init. No LDS, no __syncthreads.
__global__ __launch_bounds__(256, 2) void k_qkv_attn(
    const unsigned short* __restrict__ A,   // xnt fragment-major
    const unsigned short* __restrict__ B,   // wqb fragment-major
    const float* __restrict__ bq,
    unsigned short* __restrict__ attn_out) {
  int h = blockIdx.x;                       // head (fast dim -> A reuse via L2/L3)
  int row0 = blockIdx.y * 128;
  int t = threadIdx.x;
  int w = t >> 6, lane = t & 63;
  int lm = lane & 15, q4 = lane >> 4;

  size_t aBase = (size_t)((row0 + w*32) >> 4) * 4096 + (size_t)lane * 8;  // shorts
  size_t bBase = (size_t)h * 49152 + (size_t)lane * 8;

  facc4 acc[2][12];
  #pragma unroll
  for (int j = 0; j < 12; ++j) {
    facc4 bb = *(const facc4*)(bq + (j >> 2)*256 + h*64 + (j & 3)*16 + q4*4);
    acc[0][j] = bb; acc[1][j] = bb;
  }

  #pragma unroll
  for (int kk = 0; kk < 8; ++kk) {
    bfrag8 a0 = *(const bfrag8*)(A + aBase + (size_t)kk*512);
    bfrag8 a1 = *(const bfrag8*)(A + aBase + 4096 + (size_t)kk*512);
    #pragma unroll
    for (int j = 0; j < 12; ++j) {
      bfrag8 wf = *(const bfrag8*)(B + bBase + (size_t)(kk*12 + j)*512);
      acc[0][j] = __builtin_amdgcn_mfma_f32_16x16x32_bf16(wf, a0, acc[0][j], 0, 0, 0);
      acc[1][j] = __builtin_amdgcn_mfma_f32_16x16x32_bf16(wf, a1, acc[1][j], 0, 0, 0);
    }
  }

  // in-register cross-view attention per 16-row panel
  #pragma unroll
  for (int i = 0; i < 2; ++i) {
    // lane holds 16 of the 64 d's (d = jj*16 + q4*4 + r) for row-slot lm;
    // cross-view partner (same pixel, other view) = lane^8 under sigma order.
    float s_same = 0.f, s_cross = 0.f;
    #pragma unroll
    for (int jj = 0; jj < 4; ++jj) {
      #pragma unroll
      for (int r = 0; r < 4; ++r) {
        float qv = acc[i][jj][r];
        float kv = acc[i][4 + jj][r];
        float kx = __shfl_xor(kv, 8);
        s_same  += qv * kv;
        s_cross += qv * kx;
      }
    }
    // reduce partial dots over the 4 lane-groups (same slot in lanes l, l^16, l^32, l^48)
    s_same  += __shfl_xor(s_same, 16);  s_same  += __shfl_xor(s_same, 32);
    s_cross += __shfl_xor(s_cross, 16); s_cross += __shfl_xor(s_cross, 32);
    float s0 = s_same * 0.125f, s1 = s_cross * 0.125f;   // scale = 64^-0.5
    float m = fmaxf(s0, s1);
    float e0 = __expf(s0 - m), e1 = __expf(s1 - m);
    float inv = 1.f / (e0 + e1);
    float w_self = e0 * inv, w_cross = e1 * inv;

    // output address: slot lm -> pixel pg = (rg>>1)+(lm&7), view = lm>>3
    int rg = row0 + w*32 + i*16;
    int pg = (rg >> 1) + (lm & 7);
    int v = lm >> 3;
    int pair = pg >> 14, p = pg & 16383;
    unsigned short* dst = attn_out + ((size_t)((pair*2 + v)*16384 + p))*256 + h*64 + q4*4;
    #pragma unroll
    for (int jj = 0; jj < 4; ++jj) {
      float o[4];
      #pragma unroll
      for (int r = 0; r < 4; ++r) {
        float vv = acc[i][8 + jj][r];
        float vx = __shfl_xor(vv, 8);
        o[r] = w_self * vv + w_cross * vx;
      }
      uint2 pk;
      pk.x = (unsigned int)f2b(o[0]) | ((unsigned int)f2b(o[1]) << 16);
      pk.y = (unsigned int)f2b(o[2]) | ((unsigned int)f2b(o[3]) << 16);
      *(uint2*)(dst + jj*16) = pk;
    }
  }
}

// ---- proj GEMM: D[o][n] = wp[o][k] . attn_out[n][k] + bp[o] + x, fp32 out, batched ----
__global__ __launch_bounds__(256, 2) void k_gemm_proj(
    const unsigned short* __restrict__ A,   // wpb [256][256]
    const unsigned short* __restrict__ B,   // attn_out [131072][256]
    const float* __restrict__ bias,
    const float* __restrict__ x,
    float* __restrict__ out) {
  __shared__ unsigned short As[128][LDSP];
  __shared__ unsigned short Bs[128][LDSP];
  int col0 = blockIdx.x * 128;   // n in [0,131072)
  int row0 = blockIdx.y * 128;   // o in [0,256)
  int t = threadIdx.x;
  int w = t >> 6, lane = t & 63;
  int wm = w & 1, wn = w >> 1;
  int lm = lane & 15, q = lane >> 4;
  facc4 acc[4][4] = {};
  for (int kc = 0; kc < 4; ++kc) {
    for (int i = 0; i < 4; ++i) {
      int flat = i * 256 + t;
      int r = flat >> 3, g = flat & 7;
      *(us8*)(&As[r][g*8]) = *(const us8*)(A + (size_t)(row0 + r)*256 + kc*BK + g*8);
      *(us8*)(&Bs[r][g*8]) = *(const us8*)(B + (size_t)(col0 + r)*256 + kc*BK + g*8);
    }
    __syncthreads();
    for (int ks = 0; ks < 2; ++ks) {
      bfrag8 a[4], b[4];
      for (int i = 0; i < 4; ++i) a[i] = *(const bfrag8*)(&As[wm*64 + i*16 + lm][ks*32 + q*8]);
      for (int j = 0; j < 4; ++j) b[j] = *(const bfrag8*)(&Bs[wn*64 + j*16 + lm][ks*32 + q*8]);
      for (int i = 0; i < 4; ++i)
        for (int j = 0; j < 4; ++j)
          acc[i][j] = __builtin_amdgcn_mfma_f32_16x16x32_bf16(a[i], b[j], acc[i][j], 0, 0, 0);
    }
    __syncthreads();
  }
  for (int i = 0; i < 4; ++i) {
    for (int r = 0; r < 4; ++r) {
      int o = row0 + wm*64 + i*16 + q*4 + r;
      float bi = bias[o];
      for (int j = 0; j < 4; ++j) {
        int n = col0 + wn*64 + j*16 + lm;
        int bv = n >> 14, p = n & 16383;
        size_t gidx = ((size_t)bv * 256 + o) * 16384 + p;
        out[gidx] = acc[i][j][r] + bi + x[gidx];
      }
    }
  }
}

extern "C" void kernel_launch(void* const* d_in, const int* in_sizes, int n_in,
                              void* d_out, int out_size, void* d_ws, size_t ws_size,
                              hipStream_t stream) {
  const float* x     = (const float*)d_in[0];
  const float* gamma = (const float*)d_in[1];
  const float* beta  = (const float*)d_in[2];
  const float* wq    = (const float*)d_in[3];
  const float* bq    = (const float*)d_in[4];
  const float* wp    = (const float*)d_in[5];
  const float* bp    = (const float*)d_in[6];
  float* out = (float*)d_out;

  char* ws = (char*)d_ws;
  float* red   = (float*)ws;                    // 512 B (zeroed below)
  float* stats = (float*)(ws + 512);            // 512 B
  unsigned short* wqb = (unsigned short*)(ws + 1024);            // 393216 B (fragment-major)
  unsigned short* wpb = (unsigned short*)(ws + 1024 + 393216);   // 131072 B
  size_t off = 1024 + 393216 + 131072;
  unsigned short* xnt = (unsigned short*)(ws + off); off += (size_t)NROWS * 256 * 2;  // 67 MB
  unsigned short* att = (unsigned short*)(ws + off);                                   // 67 MB

  hipMemsetAsync(red, 0, 1024, stream);
  k_cast<<<1024, 256, 0, stream>>>(wq, wp, wqb, wpb);
  k_red<<<512, 256, 0, stream>>>(x, red);
  k_fin<<<1, 64, 0, stream>>>(red, stats);
  k_norm_t<<<8192, 256, 0, stream>>>(x, stats, gamma, beta, xnt);
  k_qkv_attn<<<dim3(4, 1024), 256, 0, stream>>>(xnt, wqb, bq, att);
  k_gemm_proj<<<dim3(1024, 2), 256, 0, stream>>>(wpb, att, bp, x, out);
}

// Round 6
// 411.562 us; speedup vs baseline: 1.1597x; 1.1597x over previous
//
#include <hip/hip_runtime.h>
#include <stdint.h>

#define HW 16384
#define CCH 256
#define NROWS 131072          // 4 pairs * 16384 px * 2 views (interleaved rows)
#define GROUP_ELEMS 524288    // 32 ch * 16384 px
#define BK 64
#define LDSP 72               // proj staging row stride (bf16): 144 B, 16B aligned

typedef __attribute__((ext_vector_type(8))) short bfrag8;
typedef __attribute__((ext_vector_type(8))) unsigned short us8;
typedef __attribute__((ext_vector_type(4))) float facc4;

static __device__ __forceinline__ unsigned short f2b(float f) {
  union { float f; unsigned int u; } x; x.f = f;
  unsigned int r = x.u + 0x7FFFu + ((x.u >> 16) & 1u);
  return (unsigned short)(r >> 16);
}
static __device__ __forceinline__ float b2f(unsigned short h) {
  union { float f; unsigned int u; } x; x.u = ((unsigned int)h) << 16;
  return x.f;
}

// async global->LDS, 16B per lane: LDS dst is wave-uniform base (+lane*16 by HW),
// global src is per-lane.
static __device__ __forceinline__ void gload_lds16(const unsigned short* g, unsigned short* l) {
  __builtin_amdgcn_global_load_lds(
      (const __attribute__((address_space(1))) unsigned int*)g,
      (__attribute__((address_space(3))) unsigned int*)l, 16, 0, 0);
}

// ---------------- GroupNorm stats ----------------
__global__ void k_red(const float* __restrict__ x, float* __restrict__ red) {
  int gg = blockIdx.x >> 3, sp = blockIdx.x & 7;   // 64 groups x 8 splits
  const float4* p = (const float4*)(x + (size_t)gg * GROUP_ELEMS + (size_t)sp * 65536);
  float s = 0.f, ss = 0.f;
  for (int i = 0; i < 64; ++i) {
    float4 v = p[i * 256 + threadIdx.x];
    s  += v.x + v.y + v.z + v.w;
    ss += v.x*v.x + v.y*v.y + v.z*v.z + v.w*v.w;
  }
  for (int off = 32; off; off >>= 1) { s += __shfl_xor(s, off); ss += __shfl_xor(ss, off); }
  __shared__ float ls[4], lss[4];
  int w = threadIdx.x >> 6;
  if ((threadIdx.x & 63) == 0) { ls[w] = s; lss[w] = ss; }
  __syncthreads();
  if (threadIdx.x == 0) {
    float S = ls[0]+ls[1]+ls[2]+ls[3], SS = lss[0]+lss[1]+lss[2]+lss[3];
    atomicAdd(&red[gg*2], S); atomicAdd(&red[gg*2+1], SS);
  }
}

__global__ void k_fin(const float* __restrict__ red, float* __restrict__ stats) {
  int g = threadIdx.x;
  float s = red[g*2], ss = red[g*2+1];
  float mean = s / (float)GROUP_ELEMS;
  float var = ss / (float)GROUP_ELEMS - mean*mean;
  stats[g*2] = mean;
  stats[g*2+1] = rsqrtf(var + 1e-5f);
}

// ------- weight cast -------
// wqb fragment-major: [h][kk=0..7][j=0..11][lane][8], frag = 512 shorts.
// Fragment lane (lm,q4) holds W-row (j*16+lm), k-elems kk*32 + q4*8 + e.
// wpb: plain [256][256] bf16 (proj unchanged).
__global__ void k_cast(const float* __restrict__ wq, const float* __restrict__ wp,
                       unsigned short* __restrict__ wqb, unsigned short* __restrict__ wpb) {
  int i = blockIdx.x * 256 + threadIdx.x;   // grid 1024 -> 262144 = 196608 + 65536 exactly
  if (i < 768*256) {
    int h = i / 49152;
    int rem = i % 49152;
    int kk = rem / 6144;                // 0..7
    int rem2 = rem % 6144;
    int j = rem2 >> 9;                  // 0..11
    int lane = (rem2 >> 3) & 63;
    int e = rem2 & 7;
    int q4 = lane >> 4, lm = lane & 15;
    int cl = j*16 + lm;                 // head-local output col 0..191
    int part = cl >> 6, d = cl & 63;
    int o = part*256 + h*64 + d;        // original wq row
    int k = kk*32 + q4*8 + e;
    wqb[i] = f2b(wq[o*256 + k]);
  } else {
    int j = i - 768*256;
    wpb[j] = f2b(wp[j]);
  }
}

// ---- norm + transpose: x[bv][c][p] fp32 -> xnt fragment-major bf16 ----
// Logical GEMM row R = pair*32768 + P*2 + v (P = pixel, v = view).
// Panel n = R>>4 (4096 shorts); within panel, kk-block (512 shorts) holds
// 16 slots x 32 channels. Slot s holds logical row 16n + sigma(s),
// sigma(s) = 2*(s&7) + (s>>3)  (view = s>>3 -> cross-view partner = lane^8).
// addr_shorts = n*4096 + kk*512 + q4*128 + s*8 + e, channel c = kk*32+q4*8+e.
__global__ void k_norm_t(const float* __restrict__ x, const float* __restrict__ stats,
                         const float* __restrict__ gamma, const float* __restrict__ beta,
                         unsigned short* __restrict__ xnt) {
  __shared__ float tile[64][65];
  int bx = blockIdx.x;               // 8192 blocks: bv(8) x ptile(256) x ctile(4)
  int bv = bx >> 10;
  int rem = bx & 1023;
  int p0 = (rem >> 2) * 64, c0 = (rem & 3) * 64;
  int pair = bv >> 1, v = bv & 1;
  int t = threadIdx.x;
  int p_off = t & 63, c4 = t >> 6;
  const float* xsrc = x + (size_t)bv * CCH * HW;
  for (int cc = 0; cc < 16; ++cc) {
    int c_loc = c4 * 16 + cc;
    int c = c0 + c_loc;
    float val = xsrc[(size_t)c * HW + p0 + p_off];
    int g = bv * 8 + (c >> 5);
    float xn = (val - stats[g*2]) * stats[g*2+1] * gamma[c] + beta[c];
    tile[p_off][c_loc] = xn;
  }
  __syncthreads();
  for (int it = 0; it < 8; ++it) {
    int u = it * 256 + t;
    int p = u >> 5, c2 = u & 31;
    int c = c0 + c2*2;
    unsigned int pk = (unsigned int)f2b(tile[p][c2*2]) | ((unsigned int)f2b(tile[p][c2*2+1]) << 16);
    int P = p0 + p;                          // pixel within pair
    int n = pair*2048 + (P >> 3);            // panel
    int s = (P & 7) + 8*v;                   // slot within panel
    size_t addr = (size_t)n*4096 + (size_t)(c >> 5)*512 + (size_t)((c & 31) >> 3)*128
                + (size_t)s*8 + (c & 7);
    *(unsigned int*)(xnt + addr) = pk;
  }
}

// ------- fused QKV GEMM + cross-view attention -------
// Wave owns 32 rows (2 panels) x 192 cols (one head); acc[2][12] = 96 regs.
// A fragments: direct-global 1KB wave loads (fragment-major xnt).
// B fragments: staged ONCE per block via global_load_lds (kills the 4x/wave
// redundant B stream that was the r5 bottleneck): per 64-K chunk, 24 frags
// = 24KB LDS, 6 gload_lds per wave; consume via linear conflict-free
// ds_read_b128. In-register cross-view attention epilogue (verified r5).
__global__ __launch_bounds__(256, 2) void k_qkv_attn(
    const unsigned short* __restrict__ A,   // xnt fragment-major
    const unsigned short* __restrict__ B,   // wqb fragment-major
    const float* __restrict__ bq,
    unsigned short* __restrict__ attn_out) {
  __shared__ __align__(16) unsigned short Blds[24 * 512];   // 24 KB
  int h = blockIdx.x;                       // head (fast dim -> A-tile L2 reuse)
  int row0 = blockIdx.y * 128;
  int t = threadIdx.x;
  int w = t >> 6, lane = t & 63;
  int lm = lane & 15, q4 = lane >> 4;

  size_t aBase = (size_t)((row0 + w*32) >> 4) * 4096 + (size_t)lane * 8;  // shorts
  const unsigned short* Bh = B + (size_t)h * 49152;

  facc4 acc[2][12];
  #pragma unroll
  for (int j = 0; j < 12; ++j) {
    facc4 bb = *(const facc4*)(bq + (j >> 2)*256 + h*64 + (j & 3)*16 + q4*4);
    acc[0][j] = bb; acc[1][j] = bb;
  }

  #pragma unroll
  for (int c = 0; c < 4; ++c) {            // 64-wide K chunks
    // stage 24 B fragments of this chunk (6 per wave), async to LDS
    #pragma unroll
    for (int i = 0; i < 6; ++i) {
      int f = w*6 + i;                     // 0..23 = kk2*12 + j
      gload_lds16(Bh + (size_t)(c*24 + f)*512 + (size_t)lane*8, &Blds[f*512]);
    }
    // prefetch the chunk's 4 A fragments (latency overlaps staging drain)
    bfrag8 a[2][2];
    #pragma unroll
    for (int kk2 = 0; kk2 < 2; ++kk2)
      #pragma unroll
      for (int p = 0; p < 2; ++p)
        a[kk2][p] = *(const bfrag8*)(A + aBase + (size_t)p*4096 + (size_t)(c*2 + kk2)*512);
    __syncthreads();                       // vmcnt(0) drain -> staged B visible
    #pragma unroll
    for (int kk2 = 0; kk2 < 2; ++kk2) {
      #pragma unroll
      for (int j = 0; j < 12; ++j) {
        bfrag8 wf = *(const bfrag8*)(&Blds[(kk2*12 + j)*512 + lane*8]);
        acc[0][j] = __builtin_amdgcn_mfma_f32_16x16x32_bf16(wf, a[kk2][0], acc[0][j], 0, 0, 0);
        acc[1][j] = __builtin_amdgcn_mfma_f32_16x16x32_bf16(wf, a[kk2][1], acc[1][j], 0, 0, 0);
      }
    }
    __syncthreads();                       // protect Blds before next chunk
  }

  // in-register cross-view attention per 16-row panel
  #pragma unroll
  for (int i = 0; i < 2; ++i) {
    // lane holds 16 of the 64 d's (d = jj*16 + q4*4 + r) for row-slot lm;
    // cross-view partner (same pixel, other view) = lane^8 under sigma order.
    float s_same = 0.f, s_cross = 0.f;
    #pragma unroll
    for (int jj = 0; jj < 4; ++jj) {
      #pragma unroll
      for (int r = 0; r < 4; ++r) {
        float qv = acc[i][jj][r];
        float kv = acc[i][4 + jj][r];
        float kx = __shfl_xor(kv, 8);
        s_same  += qv * kv;
        s_cross += qv * kx;
      }
    }
    // reduce partial dots over the 4 lane-groups (same slot in lanes l, l^16, l^32, l^48)
    s_same  += __shfl_xor(s_same, 16);  s_same  += __shfl_xor(s_same, 32);
    s_cross += __shfl_xor(s_cross, 16); s_cross += __shfl_xor(s_cross, 32);
    float s0 = s_same * 0.125f, s1 = s_cross * 0.125f;   // scale = 64^-0.5
    float m = fmaxf(s0, s1);
    float e0 = __expf(s0 - m), e1 = __expf(s1 - m);
    float inv = 1.f / (e0 + e1);
    float w_self = e0 * inv, w_cross = e1 * inv;

    // output address: slot lm -> pixel pg = (rg>>1)+(lm&7), view = lm>>3
    int rg = row0 + w*32 + i*16;
    int pg = (rg >> 1) + (lm & 7);
    int v = lm >> 3;
    int pair = pg >> 14, p = pg & 16383;
    unsigned short* dst = attn_out + ((size_t)((pair*2 + v)*16384 + p))*256 + h*64 + q4*4;
    #pragma unroll
    for (int jj = 0; jj < 4; ++jj) {
      float o[4];
      #pragma unroll
      for (int r = 0; r < 4; ++r) {
        float vv = acc[i][8 + jj][r];
        float vx = __shfl_xor(vv, 8);
        o[r] = w_self * vv + w_cross * vx;
      }
      uint2 pk;
      pk.x = (unsigned int)f2b(o[0]) | ((unsigned int)f2b(o[1]) << 16);
      pk.y = (unsigned int)f2b(o[2]) | ((unsigned int)f2b(o[3]) << 16);
      *(uint2*)(dst + jj*16) = pk;
    }
  }
}

// ---- proj GEMM: D[o][n] = wp[o][k] . attn_out[n][k] + bp[o] + x, fp32 out, batched ----
__global__ __launch_bounds__(256, 2) void k_gemm_proj(
    const unsigned short* __restrict__ A,   // wpb [256][256]
    const unsigned short* __restrict__ B,   // attn_out [131072][256]
    const float* __restrict__ bias,
    const float* __restrict__ x,
    float* __restrict__ out) {
  __shared__ unsigned short As[128][LDSP];
  __shared__ unsigned short Bs[128][LDSP];
  int col0 = blockIdx.x * 128;   // n in [0,131072)
  int row0 = blockIdx.y * 128;   // o in [0,256)
  int t = threadIdx.x;
  int w = t >> 6, lane = t & 63;
  int wm = w & 1, wn = w >> 1;
  int lm = lane & 15, q = lane >> 4;
  facc4 acc[4][4] = {};
  for (int kc = 0; kc < 4; ++kc) {
    for (int i = 0; i < 4; ++i) {
      int flat = i * 256 + t;
      int r = flat >> 3, g = flat & 7;
      *(us8*)(&As[r][g*8]) = *(const us8*)(A + (size_t)(row0 + r)*256 + kc*BK + g*8);
      *(us8*)(&Bs[r][g*8]) = *(const us8*)(B + (size_t)(col0 + r)*256 + kc*BK + g*8);
    }
    __syncthreads();
    for (int ks = 0; ks < 2; ++ks) {
      bfrag8 a[4], b[4];
      for (int i = 0; i < 4; ++i) a[i] = *(const bfrag8*)(&As[wm*64 + i*16 + lm][ks*32 + q*8]);
      for (int j = 0; j < 4; ++j) b[j] = *(const bfrag8*)(&Bs[wn*64 + j*16 + lm][ks*32 + q*8]);
      for (int i = 0; i < 4; ++i)
        for (int j = 0; j < 4; ++j)
          acc[i][j] = __builtin_amdgcn_mfma_f32_16x16x32_bf16(a[i], b[j], acc[i][j], 0, 0, 0);
    }
    __syncthreads();
  }
  for (int i = 0; i < 4; ++i) {
    for (int r = 0; r < 4; ++r) {
      int o = row0 + wm*64 + i*16 + q*4 + r;
      float bi = bias[o];
      for (int j = 0; j < 4; ++j) {
        int n = col0 + wn*64 + j*16 + lm;
        int bv = n >> 14, p = n & 16383;
        size_t gidx = ((size_t)bv * 256 + o) * 16384 + p;
        out[gidx] = acc[i][j][r] + bi + x[gidx];
      }
    }
  }
}

extern "C" void kernel_launch(void* const* d_in, const int* in_sizes, int n_in,
                              void* d_out, int out_size, void* d_ws, size_t ws_size,
                              hipStream_t stream) {
  const float* x     = (const float*)d_in[0];
  const float* gamma = (const float*)d_in[1];
  const float* beta  = (const float*)d_in[2];
  const float* wq    = (const float*)d_in[3];
  const float* bq    = (const float*)d_in[4];
  const float* wp    = (const float*)d_in[5];
  const float* bp    = (const float*)d_in[6];
  float* out = (float*)d_out;

  char* ws = (char*)d_ws;
  float* red   = (float*)ws;                    // 512 B (zeroed below)
  float* stats = (float*)(ws + 512);            // 512 B
  unsigned short* wqb = (unsigned short*)(ws + 1024);            // 393216 B (fragment-major)
  unsigned short* wpb = (unsigned short*)(ws + 1024 + 393216);   // 131072 B
  size_t off = 1024 + 393216 + 131072;
  unsigned short* xnt = (unsigned short*)(ws + off); off += (size_t)NROWS * 256 * 2;  // 67 MB
  unsigned short* att = (unsigned short*)(ws + off);                                   // 67 MB

  hipMemsetAsync(red, 0, 1024, stream);
  k_cast<<<1024, 256, 0, stream>>>(wq, wp, wqb, wpb);
  k_red<<<512, 256, 0, stream>>>(x, red);
  k_fin<<<1, 64, 0, stream>>>(red, stats);
  k_norm_t<<<8192, 256, 0, stream>>>(x, stats, gamma, beta, xnt);
  k_qkv_attn<<<dim3(4, 1024), 256, 0, stream>>>(xnt, wqb, bq, att);
  k_gemm_proj<<<dim3(1024, 2), 256, 0, stream>>>(wpb, att, bp, x, out);
}